// Round 4
// baseline (492.629 us; speedup 1.0000x reference)
//
#include <hip/hip_runtime.h>
#include <hip/hip_bf16.h>
#include <math.h>

#define CIN 128
#define HH 128
#define WW 128
#define HWX (HH*WW)
#define COUT 256
#define NB 4

typedef __attribute__((ext_vector_type(8))) short short8;
typedef __attribute__((ext_vector_type(4))) float f32x4;
typedef __attribute__((ext_vector_type(2))) float f2v;

__device__ __forceinline__ unsigned short f2bf(float f) {
    union { float f; unsigned int u; } c; c.f = f;
    unsigned int u = c.u + 0x7FFF + ((c.u >> 16) & 1);   // RNE
    return (unsigned short)(u >> 16);
}

// ---------------------------------------------------------------------------
// Prep 1: pack offset/mod conv weights contiguously: wofft[c][t][28]
// ---------------------------------------------------------------------------
__global__ __launch_bounds__(256) void wpack_kernel(
    const float* __restrict__ offw, const float* __restrict__ modw,
    float* __restrict__ wofft)
{
    int i = blockIdx.x * 256 + threadIdx.x;
    if (i >= CIN * 9 * 28) return;
    int o = i % 28;
    int t = (i / 28) % 9;
    int c = i / 252;
    float v = 0.f;
    if (o < 18)      v = offw[(o * CIN + c) * 9 + t];
    else if (o < 27) v = modw[((o - 18) * CIN + c) * 9 + t];
    wofft[i] = v;
}

// ---------------------------------------------------------------------------
// Prep 2: bf16 A-fragment image for MFMA (layout verified R2/R3).
//   L = ((((kk*4+cc)*16 + mt)*64 + l)*8 + j)
//   o = mt*16 + (l&15);  c = cc*32 + (l>>4)*8 + j;  value = wgt[o][c][kk]
// ---------------------------------------------------------------------------
__global__ __launch_bounds__(256) void wimg_kernel(
    const float* __restrict__ wgt, unsigned short* __restrict__ wAi)
{
    int i = blockIdx.x * 256 + threadIdx.x;   // < 294912
    int j  = i & 7;
    int l  = (i >> 3) & 63;
    int mt = (i >> 9) & 15;
    int cc = (i >> 13) & 3;
    int kk = i >> 15;
    int o = mt * 16 + (l & 15);
    int c = cc * 32 + (l >> 4) * 8 + j;
    wAi[i] = f2bf(wgt[(o * CIN + c) * 9 + kk]);
}

// ---------------------------------------------------------------------------
// Kernel A: fused offset/mask conv + sampling-table epilogue.
// 128 threads = 2 waves; wave w computes channels [w*64, w*64+64) for a
// 32x2 pixel tile; LDS combine; wave 0 runs the epilogue.
// XCD-banded swizzle: F&7 -> (batch, y-half) band.
// New table packing for float2 gathers:
//   pk = r0c | r1c<<7 | cb<<14,  w4 = (a*wl, a*wr, bb*wl, bb*wr)
//   value = w.x*X[r0,cb] + w.y*X[r0,cb+1] + w.z*X[r1,cb] + w.w*X[r1,cb+1]
// ---------------------------------------------------------------------------
__global__ __launch_bounds__(128) void offmask_kernel(
    const float* __restrict__ x, const float* __restrict__ wofft,
    const float* __restrict__ offb, const float* __restrict__ modb,
    unsigned int* __restrict__ pk_out, float4* __restrict__ w4_out)
{
    __shared__ float xs[2176];   // staging 16ch x 4row x 34col; reused as combine

    const int tid = threadIdx.x;
    const int wave = tid >> 6;
    const int l = tid & 63;
    const int F = blockIdx.x;                 // 0..1023
    const int xcd = F & 7, s = F >> 3;        // s: 0..127
    const int b = xcd >> 1;
    const int yh = xcd & 1;
    const int yt = s >> 2, xq = s & 3;
    const int row0 = yh * 64 + yt * 2;
    const int wo0 = xq * 32;
    const int lx = l & 31, ry = l >> 5;
    const int ho = row0 + ry, wo = wo0 + lx;
    const int wch = __builtin_amdgcn_readfirstlane(wave) * 64;

    float acc[27];
#pragma unroll
    for (int o = 0; o < 27; ++o) acc[o] = 0.f;

#pragma unroll 1
    for (int it = 0; it < 8; ++it) {
        // stage 16 channels (8 per wave-half): rows row0-1..+2, cols wo0-1..+32
#pragma unroll
        for (int rep = 0; rep < 17; ++rep) {
            int e = tid + rep * 128;          // 2176 = 17*128 exact
            int u = e / 136;
            int rem = e - u * 136;
            int r = rem / 34;
            int col = rem - r * 34;
            int ch = (u >> 3) * 64 + it * 8 + (u & 7);
            int gy = row0 - 1 + r, gx = wo0 - 1 + col;
            float v = 0.f;
            if (gy >= 0 && gy < HH && gx >= 0 && gx < WW)
                v = x[((b * CIN + ch) << 14) + (gy << 7) + gx];
            xs[e] = v;
        }
        __syncthreads();

#pragma unroll 1
        for (int c = 0; c < 8; ++c) {
            int ch = wch + it * 8 + c;        // wave-uniform -> s_load weights
            int base = (wave * 8 + c) * 136;
            float xv[3][3];
#pragma unroll
            for (int dy = 0; dy < 3; ++dy)
#pragma unroll
                for (int dx = 0; dx < 3; ++dx)
                    xv[dy][dx] = xs[base + (ry + dy) * 34 + lx + dx];
#pragma unroll
            for (int t = 0; t < 9; ++t) {
                const float* wp = wofft + (ch * 9 + t) * 28;
                float xt = xv[t / 3][t % 3];
#pragma unroll
                for (int o = 0; o < 27; ++o)
                    acc[o] = fmaf(xt, wp[o], acc[o]);
            }
        }
        __syncthreads();
    }

    // combine halves
    float* cmb = xs;   // 27*64 = 1728 floats
    if (wave == 1) {
#pragma unroll
        for (int o = 0; o < 27; ++o) cmb[o * 64 + l] = acc[o];
    }
    __syncthreads();
    if (wave == 0) {
#pragma unroll
        for (int o = 0; o < 27; ++o) acc[o] += cmb[o * 64 + l];

        const int pix = (ho << 7) + wo;
#pragma unroll
        for (int kk = 0; kk < 9; ++kk) {
            float oy = acc[2 * kk] + offb[2 * kk];
            float ox = acc[2 * kk + 1] + offb[2 * kk + 1];
            float mt = acc[18 + kk] + modb[kk];
            float m = 2.f / (1.f + expf(-mt));
            float py = (float)(ho - 1 + kk / 3) + oy;
            float px = (float)(wo - 1 + kk % 3) + ox;
            float y0f = floorf(py), x0f = floorf(px);
            float wy = py - y0f, wx = px - x0f;
            int y0 = (int)y0f, x0 = (int)x0f;
            int y1 = y0 + 1, x1 = x0 + 1;
            float vy0 = (y0 >= 0 && y0 < HH) ? 1.f : 0.f;
            float vy1 = (y1 >= 0 && y1 < HH) ? 1.f : 0.f;
            float vx0 = (x0 >= 0 && x0 < WW) ? 1.f : 0.f;
            float vx1 = (x1 >= 0 && x1 < WW) ? 1.f : 0.f;
            float a  = m * (1.f - wy) * vy0;
            float bb = m * wy * vy1;
            float u  = (1.f - wx) * vx0;
            float vv = wx * vx1;
            int y0c = min(max(y0, 0), HH - 1), y1c = min(max(y1, 0), HH - 1);
            int x0c = min(max(x0, 0), WW - 1), x1c = min(max(x1, 0), WW - 1);
            int cb = min(max(x0, 0), WW - 2);
            float wl = ((x0c == cb) ? u : 0.f) + ((x1c == cb) ? vv : 0.f);
            float wr = ((x0c == cb + 1) ? u : 0.f) + ((x1c == cb + 1) ? vv : 0.f);
            unsigned int pkv = (unsigned)y0c | ((unsigned)y1c << 7) |
                               ((unsigned)cb << 14);
            int gi = ((b * 9 + kk) << 14) + pix;
            pk_out[gi] = pkv;
            w4_out[gi] = make_float4(a * wl, a * wr, bb * wl, bb * wr);
        }
    }
}

// ---------------------------------------------------------------------------
// Kernel B: software-pipelined barrier-free deformable GEMM (MFMA bf16).
// Wave w: N-tile w (16 px), all 16 M-tiles (full Cout). Per 32-ch chunk:
// issue A frags (L2-hot), issue NEXT chunk's float2 gathers (stay in flight
// across the MFMAs), convert current prefetched gathers, 16 MFMAs.
// XCD-banded swizzle for x L2 locality. No LDS, no __syncthreads.
// ---------------------------------------------------------------------------
__global__ __launch_bounds__(256) void dgemm_kernel(
    const float* __restrict__ x, const unsigned short* __restrict__ wAi,
    const unsigned int* __restrict__ pk, const float4* __restrict__ w4,
    float* __restrict__ out)
{
    const int tid  = threadIdx.x;
    const int l    = tid & 63;
    const int wave = tid >> 6;
    const int F = blockIdx.x;                  // 0..1023
    const int xcd = F & 7, s = F >> 3;         // s: 0..127
    const int b = xcd >> 1;
    const int row = (xcd & 1) * 64 + (s >> 1);
    const int pix0 = (row << 7) + (s & 1) * 64;
    const int q  = l >> 4;
    const int px = pix0 + wave * 16 + (l & 15);
    const float* xb = x + ((size_t)b << 21);

    f32x4 acc[16];
#pragma unroll
    for (int i = 0; i < 16; ++i) acc[i] = (f32x4){0.f, 0.f, 0.f, 0.f};

    int gi = ((b * 9) << 14) + px;
    unsigned int pkv = pk[gi];
    float4 wv = w4[gi];
    int o0 = ((pkv & 127) << 7) + (pkv >> 14);
    int o1 = (((pkv >> 7) & 127) << 7) + (pkv >> 14);

    f2v c0b[2][8], c1b[2][8];
    {   // prime pipeline: gathers for chunk (kk=0, cc=0)
        const float* p = xb + ((q * 8) << 14);
#pragma unroll
        for (int j = 0; j < 8; ++j) {
            c0b[0][j] = *(const f2v*)(p + o0);
            c1b[0][j] = *(const f2v*)(p + o1);
            p += HWX;
        }
    }
    unsigned int pkv_n = pkv;
    float4 wv_n = wv;

#pragma unroll 1
    for (int kk = 0; kk < 9; ++kk) {
#pragma unroll
        for (int cc = 0; cc < 4; ++cc) {
            // 1) A fragments for current chunk (oldest in vmcnt order)
            const short8* ab = (const short8*)(wAi + (((kk << 2) + cc) << 13)) + l;
            short8 af[16];
#pragma unroll
            for (int m = 0; m < 16; ++m) af[m] = ab[m * 64];

            // 2) prefetch next-kk descriptor 3 chunks early
            if (cc == 0) {
                int kn = (kk < 8) ? kk + 1 : 8;
                int gin = ((b * 9 + kn) << 14) + px;
                pkv_n = pk[gin];
                wv_n = w4[gin];
            }

            // 3) issue NEXT chunk's gathers (newest -> not drained by A waits)
            int o0n = o0, o1n = o1;
            if (cc == 3) {
                o0n = ((pkv_n & 127) << 7) + (pkv_n >> 14);
                o1n = (((pkv_n >> 7) & 127) << 7) + (pkv_n >> 14);
            }
            {
                int cc2 = (cc + 1) & 3;
                const float* pn = xb + (((cc2 << 5) + (q << 3)) << 14);
                int nb = (cc & 1) ^ 1;
#pragma unroll
                for (int j = 0; j < 8; ++j) {
                    c0b[nb][j] = *(const f2v*)(pn + o0n);
                    c1b[nb][j] = *(const f2v*)(pn + o1n);
                    pn += HWX;
                }
            }

            // 4) convert current chunk's prefetched gathers -> B fragment
            unsigned short v[8];
#pragma unroll
            for (int j = 0; j < 8; ++j) {
                f2v r0 = c0b[cc & 1][j], r1 = c1b[cc & 1][j];
                float val = wv.x * r0.x + wv.y * r0.y +
                            wv.z * r1.x + wv.w * r1.y;
                v[j] = f2bf(val);
            }
            short8 bfr = (short8){(short)v[0], (short)v[1], (short)v[2],
                                  (short)v[3], (short)v[4], (short)v[5],
                                  (short)v[6], (short)v[7]};

            // 5) MFMAs (waits on A frags only; prefetch stays in flight)
#pragma unroll
            for (int m = 0; m < 16; ++m)
                acc[m] = __builtin_amdgcn_mfma_f32_16x16x32_bf16(
                    af[m], bfr, acc[m], 0, 0, 0);

            if (cc == 3) { o0 = o0n; o1 = o1n; wv = wv_n; }
        }
    }

    // epilogue: C/D layout col=lane&15 (=px), row=(lane>>4)*4+reg
    const int crow = q * 4;
#pragma unroll
    for (int mt = 0; mt < 16; ++mt) {
#pragma unroll
        for (int r = 0; r < 4; ++r) {
            int o = mt * 16 + crow + r;
            out[(((size_t)(b * COUT + o)) << 14) + px] = acc[mt][r];
        }
    }
}

// ---------------------------------------------------------------------------
extern "C" void kernel_launch(void* const* d_in, const int* in_sizes, int n_in,
                              void* d_out, int out_size, void* d_ws, size_t ws_size,
                              hipStream_t stream)
{
    const float* x    = (const float*)d_in[0];
    const float* offw = (const float*)d_in[1];
    const float* offb = (const float*)d_in[2];
    const float* modw = (const float*)d_in[3];
    const float* modb = (const float*)d_in[4];
    const float* wgt  = (const float*)d_in[5];
    float* out = (float*)d_out;

    char* wsb = (char*)d_ws;
    unsigned int*   pkp   = (unsigned int*)wsb;                    //  2,359,296 B
    float4*         w4p   = (float4*)(wsb + 2359296);              //  9,437,184 B
    unsigned short* wAi   = (unsigned short*)(wsb + 11796480);     //    589,824 B
    float*          wofft = (float*)(wsb + 12386304);              //    129,024 B

    wpack_kernel<<<dim3((CIN * 9 * 28 + 255) / 256), 256, 0, stream>>>(offw, modw, wofft);
    wimg_kernel<<<dim3(COUT * CIN * 9 / 256), 256, 0, stream>>>(wgt, wAi);
    offmask_kernel<<<dim3(1024), 128, 0, stream>>>(x, wofft, offb, modb, pkp, w4p);
    dgemm_kernel<<<dim3(1024), 256, 0, stream>>>(x, wAi, pkp, w4p, out);
}

// Round 5
// 354.750 us; speedup vs baseline: 1.3887x; 1.3887x over previous
//
#include <hip/hip_runtime.h>
#include <hip/hip_bf16.h>
#include <math.h>

#define CIN 128
#define HH 128
#define WW 128
#define HWX (HH*WW)
#define COUT 256
#define NB 4

typedef __attribute__((ext_vector_type(8))) short short8;
typedef __attribute__((ext_vector_type(4))) float f32x4;
typedef __attribute__((ext_vector_type(2))) float f2v;
typedef __attribute__((ext_vector_type(8))) unsigned short ushort8;

__device__ __forceinline__ unsigned short f2bf(float f) {
    union { float f; unsigned int u; } c; c.f = f;
    unsigned int u = c.u + 0x7FFF + ((c.u >> 16) & 1);   // RNE
    return (unsigned short)(u >> 16);
}
__device__ __forceinline__ float bf2f(unsigned short u) {
    union { unsigned int u; float f; } c; c.u = ((unsigned int)u) << 16;
    return c.f;
}

// ---------------------------------------------------------------------------
// Prep 1: pack offset/mod conv weights contiguously: wofft[c][t][28]
// ---------------------------------------------------------------------------
__global__ __launch_bounds__(256) void wpack_kernel(
    const float* __restrict__ offw, const float* __restrict__ modw,
    float* __restrict__ wofft)
{
    int i = blockIdx.x * 256 + threadIdx.x;
    if (i >= CIN * 9 * 28) return;
    int o = i % 28;
    int t = (i / 28) % 9;
    int c = i / 252;
    float v = 0.f;
    if (o < 18)      v = offw[(o * CIN + c) * 9 + t];
    else if (o < 27) v = modw[((o - 18) * CIN + c) * 9 + t];
    wofft[i] = v;
}

// ---------------------------------------------------------------------------
// Prep 2: bf16 A-fragment image (layout verified R2-R4).
//   L = ((c36*16 + mt)*64 + l)*8 + j ; o = mt*16+(l&15); c = cc*32+(l>>4)*8+j
// ---------------------------------------------------------------------------
__global__ __launch_bounds__(256) void wimg_kernel(
    const float* __restrict__ wgt, unsigned short* __restrict__ wAi)
{
    int i = blockIdx.x * 256 + threadIdx.x;   // < 294912
    int j  = i & 7;
    int l  = (i >> 3) & 63;
    int mt = (i >> 9) & 15;
    int cc = (i >> 13) & 3;
    int kk = i >> 15;
    int o = mt * 16 + (l & 15);
    int c = cc * 32 + (l >> 4) * 8 + j;
    wAi[i] = f2bf(wgt[(o * CIN + c) * 9 + kk]);
}

// ---------------------------------------------------------------------------
// Kernel A1: partial offset/mask conv, 16-channel chunks (8-way split).
// grid (4,16,32): z = b*8 + chunk. 32 waves/CU when resident.
// ---------------------------------------------------------------------------
__global__ __launch_bounds__(256) void convpart_kernel(
    const float* __restrict__ x, const float* __restrict__ wofft,
    unsigned short* __restrict__ part)
{
    __shared__ float xs[8][10][34];

    const int tid = threadIdx.x;
    const int lx = tid & 31, ly = tid >> 5;
    const int z = blockIdx.z;               // b*8 + chunk
    const int b = z >> 3, chunk = z & 7;
    const int cbase = chunk * 16;
    const int ty0 = blockIdx.y * 8;
    const int tx0 = blockIdx.x * 32;
    const int ho = ty0 + ly, wo = tx0 + lx;

    float acc[27];
#pragma unroll
    for (int o = 0; o < 27; ++o) acc[o] = 0.f;

#pragma unroll 1
    for (int c0 = 0; c0 < 16; c0 += 8) {
        for (int e = tid; e < 8 * 10 * 34; e += 256) {
            int c = e / 340;
            int rem = e - c * 340;
            int r = rem / 34;
            int col = rem - r * 34;
            int gy = ty0 + r - 1, gx = tx0 + col - 1;
            float v = 0.f;
            if (gy >= 0 && gy < HH && gx >= 0 && gx < WW)
                v = x[(((b * CIN) + (cbase + c0 + c)) << 14) + (gy << 7) + gx];
            xs[c][r][col] = v;
        }
        __syncthreads();

#pragma unroll 1
        for (int c = 0; c < 8; ++c) {
            float xv[3][3];
#pragma unroll
            for (int dy = 0; dy < 3; ++dy)
#pragma unroll
                for (int dx = 0; dx < 3; ++dx)
                    xv[dy][dx] = xs[c][ly + dy][lx + dx];
#pragma unroll
            for (int t = 0; t < 9; ++t) {
                const float* wp = wofft + ((cbase + c0 + c) * 9 + t) * 28;
                float xt = xv[t / 3][t % 3];
#pragma unroll
                for (int o = 0; o < 27; ++o)
                    acc[o] = fmaf(xt, wp[o], acc[o]);
            }
        }
        __syncthreads();
    }

    const int pix = (ho << 7) + wo;
    unsigned short* pp = part + ((z * 27) << 14) + pix;
#pragma unroll
    for (int o = 0; o < 27; ++o)
        pp[o << 14] = f2bf(acc[o]);
}

// ---------------------------------------------------------------------------
// Kernel A2: combine 8 partials + sampling-table epilogue.
// float2-gather packing: pk = r0c | r1c<<7 | cb<<14,
//   w4 = (a*wl, a*wr, bb*wl, bb*wr);  cb in [0,126].
// ---------------------------------------------------------------------------
__global__ __launch_bounds__(256) void tables_kernel(
    const unsigned short* __restrict__ part, const float* __restrict__ offb,
    const float* __restrict__ modb,
    unsigned int* __restrict__ pk_out, float4* __restrict__ w4_out)
{
    const int gid = blockIdx.x * 256 + threadIdx.x;
    const int pix = gid & 16383;
    const int t = gid >> 14;                // b*9 + kk
    const int kk = t % 9;
    const int b = t / 9;
    const int ho = pix >> 7, wo = pix & 127;

    float oy = 0.f, ox = 0.f, mt = 0.f;
#pragma unroll
    for (int ch = 0; ch < 8; ++ch) {
        const unsigned short* pp = part + (((b * 8 + ch) * 27) << 14) + pix;
        oy += bf2f(pp[(2 * kk) << 14]);
        ox += bf2f(pp[(2 * kk + 1) << 14]);
        mt += bf2f(pp[(18 + kk) << 14]);
    }
    oy += offb[2 * kk];
    ox += offb[2 * kk + 1];
    mt += modb[kk];

    float m = 2.f / (1.f + expf(-mt));
    float py = (float)(ho - 1 + kk / 3) + oy;
    float px = (float)(wo - 1 + kk % 3) + ox;
    float y0f = floorf(py), x0f = floorf(px);
    float wy = py - y0f, wx = px - x0f;
    int y0 = (int)y0f, x0 = (int)x0f;
    int y1 = y0 + 1, x1 = x0 + 1;
    float vy0 = (y0 >= 0 && y0 < HH) ? 1.f : 0.f;
    float vy1 = (y1 >= 0 && y1 < HH) ? 1.f : 0.f;
    float vx0 = (x0 >= 0 && x0 < WW) ? 1.f : 0.f;
    float vx1 = (x1 >= 0 && x1 < WW) ? 1.f : 0.f;
    float a  = m * (1.f - wy) * vy0;
    float bb = m * wy * vy1;
    float u  = (1.f - wx) * vx0;
    float vv = wx * vx1;
    int y0c = min(max(y0, 0), HH - 1), y1c = min(max(y1, 0), HH - 1);
    int x0c = min(max(x0, 0), WW - 1), x1c = min(max(x1, 0), WW - 1);
    int cb = min(max(x0, 0), WW - 2);
    float wl = ((x0c == cb) ? u : 0.f) + ((x1c == cb) ? vv : 0.f);
    float wr = ((x0c == cb + 1) ? u : 0.f) + ((x1c == cb + 1) ? vv : 0.f);
    unsigned int pkv = (unsigned)y0c | ((unsigned)y1c << 7) |
                       ((unsigned)cb << 14);
    pk_out[gid] = pkv;
    w4_out[gid] = make_float4(a * wl, a * wr, bb * wl, bb * wr);
}

// ---------------------------------------------------------------------------
// Kernel G: gather/im2col -> fragment-ready bf16 samp image.
// Wave = one (16-px group, cc-half); lane l: px=(l&15), ch-octet q=(l>>4).
// samp[((g*36 + c36)*64 + l)*8 + j], g = lb*1024 + row*8 + gx16.
// XCD-banded: band = F % (nb*2) -> (batch, y-half).
// ---------------------------------------------------------------------------
__global__ __launch_bounds__(256) void gather_kernel(
    const float* __restrict__ x, const unsigned int* __restrict__ pk,
    const float4* __restrict__ w4, unsigned short* __restrict__ samp,
    int b0, int nb2)
{
    const int tid = threadIdx.x;
    const int wave = tid >> 6;
    const int l = tid & 63;
    const int F = blockIdx.x;
    const int band = F % nb2;               // nb2 = nb*2 bands
    const int s = F / nb2;                  // 0..255
    const int lb = band >> 1;
    const int b = b0 + lb;
    const int yh = band & 1;
    const int unit = s * 4 + wave;          // 0..1023
    const int cchalf = unit & 1;
    const int gb = unit >> 1;               // 0..511
    const int row = yh * 64 + (gb >> 3);
    const int gx16 = gb & 7;
    const int pix = (row << 7) + (gx16 << 4) + (l & 15);
    const int g = (lb << 10) + (row << 3) + gx16;
    const int q = l >> 4;
    const float* xb = x + ((size_t)b << 21);
    unsigned short* sg = samp + (((size_t)g * 36) << 9) + (l << 3);

#pragma unroll 1
    for (int kk = 0; kk < 9; ++kk) {
        int gi = ((b * 9 + kk) << 14) + pix;
        unsigned int pkv = pk[gi];
        float4 wv = w4[gi];
        int o0 = ((pkv & 127) << 7) + (pkv >> 14);
        int o1 = (((pkv >> 7) & 127) << 7) + (pkv >> 14);
#pragma unroll
        for (int ci = 0; ci < 2; ++ci) {
            int cc = cchalf * 2 + ci;
            const float* p = xb + (((cc << 5) + (q << 3)) << 14);
            unsigned short v[8];
#pragma unroll
            for (int j = 0; j < 8; ++j) {
                f2v r0 = *(const f2v*)(p + o0);
                f2v r1 = *(const f2v*)(p + o1);
                float val = wv.x * r0.x + wv.y * r0.y +
                            wv.z * r1.x + wv.w * r1.y;
                v[j] = f2bf(val);
                p += HWX;
            }
            ushort8 pkd = {v[0], v[1], v[2], v[3], v[4], v[5], v[6], v[7]};
            *(ushort8*)&sg[((kk << 2) + cc) << 9] = pkd;
        }
    }
}

// ---------------------------------------------------------------------------
// Kernel B: clean MFMA GEMM, both operands fragment-ready & contiguous.
// Block = 64 px x 256 Cout; wave w -> Cout [w*64,(w+1)*64), 4x4 16x16 tiles.
// Per chunk: 4 A dwordx4 (L2-hot) + 4 B dwordx4 (next-chunk prefetch,
// issued after A so the MFMA vmcnt wait never drains it) + 16 MFMA.
// No LDS, no barriers.
// ---------------------------------------------------------------------------
__global__ __launch_bounds__(256) void dgemm_kernel(
    const unsigned short* __restrict__ wAi,
    const unsigned short* __restrict__ samp,
    float* __restrict__ out, int b0)
{
    const int tid = threadIdx.x;
    const int wave = tid >> 6;
    const int l = tid & 63;
    const int bx = blockIdx.x;
    const int lb = bx >> 8;
    const int b = b0 + lb;
    const int seg = bx & 255;
    const int pix0 = seg << 6;
    const unsigned short* sb =
        samp + (((size_t)((lb << 10) + (seg << 2)) * 36) << 9) + (l << 3);
    const int NTS = 36 << 9;                // nt stride in shorts

    f32x4 acc[4][4];
#pragma unroll
    for (int i = 0; i < 4; ++i)
#pragma unroll
        for (int j = 0; j < 4; ++j) acc[i][j] = (f32x4){0.f, 0.f, 0.f, 0.f};

    short8 bf[4], bfn[4];
#pragma unroll
    for (int nt = 0; nt < 4; ++nt)
        bf[nt] = *(const short8*)(sb + nt * NTS);

#pragma unroll 1
    for (int c36 = 0; c36 < 36; ++c36) {
        // A fragments (oldest in vmcnt order)
        const unsigned short* ap = wAi + (c36 << 13) + (wave << 11) + (l << 3);
        short8 af[4];
#pragma unroll
        for (int mt = 0; mt < 4; ++mt)
            af[mt] = *(const short8*)(ap + (mt << 9));

        // prefetch next chunk's B (stays in flight across MFMAs)
        int cn = (c36 < 35) ? c36 + 1 : 35;
#pragma unroll
        for (int nt = 0; nt < 4; ++nt)
            bfn[nt] = *(const short8*)(sb + nt * NTS + (cn << 9));

#pragma unroll
        for (int mt = 0; mt < 4; ++mt)
#pragma unroll
            for (int nt = 0; nt < 4; ++nt)
                acc[mt][nt] = __builtin_amdgcn_mfma_f32_16x16x32_bf16(
                    af[mt], bf[nt], acc[mt][nt], 0, 0, 0);

#pragma unroll
        for (int nt = 0; nt < 4; ++nt) bf[nt] = bfn[nt];
    }

    // epilogue: C/D col=lane&15 (=px), row=(lane>>4)*4+reg (verified R2-R4)
    const int crow = (l >> 4) * 4;
    const int pxl = pix0 + (l & 15);
#pragma unroll
    for (int mt = 0; mt < 4; ++mt) {
#pragma unroll
        for (int nt = 0; nt < 4; ++nt) {
#pragma unroll
            for (int r = 0; r < 4; ++r) {
                int o = wave * 64 + mt * 16 + crow + r;
                out[(((size_t)(b * COUT + o)) << 14) + pxl + nt * 16] =
                    acc[mt][nt][r];
            }
        }
    }
}

// ---------------------------------------------------------------------------
extern "C" void kernel_launch(void* const* d_in, const int* in_sizes, int n_in,
                              void* d_out, int out_size, void* d_ws, size_t ws_size,
                              hipStream_t stream)
{
    const float* x    = (const float*)d_in[0];
    const float* offw = (const float*)d_in[1];
    const float* offb = (const float*)d_in[2];
    const float* modw = (const float*)d_in[3];
    const float* modb = (const float*)d_in[4];
    const float* wgt  = (const float*)d_in[5];
    float* out = (float*)d_out;

    char* wsb = (char*)d_ws;
    unsigned int*   pkp   = (unsigned int*)wsb;                    //  2,359,296 B
    float4*         w4p   = (float4*)(wsb + 2359296);              //  9,437,184 B
    unsigned short* wAi   = (unsigned short*)(wsb + 11796480);     //    589,824 B
    float*          wofft = (float*)(wsb + 12386304);              //    129,024 B
    const size_t persist = 12515328;
    unsigned short* part  = (unsigned short*)(wsb + persist);      // 28,311,552 B
    unsigned short* samp  = (unsigned short*)(wsb + persist);      // reuses part区
    const size_t SAMP1 = 37748736;   // bytes per batch of samp

    // pick largest batch-group that fits: samp overlaps dead part buffer
    int nb = 4;
    if (ws_size < persist + 4 * SAMP1) nb = 2;
    if (ws_size < persist + 2 * SAMP1) nb = 1;
    // conv phase always needs persist + 28.3MB <= persist + 1*SAMP1

    wpack_kernel<<<dim3((CIN * 9 * 28 + 255) / 256), 256, 0, stream>>>(offw, modw, wofft);
    wimg_kernel<<<dim3(COUT * CIN * 9 / 256), 256, 0, stream>>>(wgt, wAi);
    convpart_kernel<<<dim3(WW / 32, HH / 8, NB * 8), 256, 0, stream>>>(x, wofft, part);
    tables_kernel<<<dim3(NB * 9 * HWX / 256), 256, 0, stream>>>(part, offb, modb, pkp, w4p);

    for (int b0 = 0; b0 < NB; b0 += nb) {
        gather_kernel<<<dim3(nb * 512), 256, 0, stream>>>(
            x, pkp, w4p, samp, b0, nb * 2);
        dgemm_kernel<<<dim3(nb * 256), 256, 0, stream>>>(wAi, samp, out, b0);
    }
}